// Round 4
// baseline (240.075 us; speedup 1.0000x reference)
//
#include <hip/hip_runtime.h>
#include <hip/hip_bf16.h>

#define NB 128
#define NP 8732
#define NO 32
#define NC 21
#define NCHUNK 35   // k_loss grid.x

// ---------------- workspace layout (no zero-init required anywhere) ----------
// pfor   : int[NB*NO]        @ 0        per-(b,o) argmax prior (plain store)
// pd0    : double[NB*35]     @ 16384    per-loss-block pos_conf partial
// pd1    : double[NB*35]     @ 52224    per-loss-block loc partial
// pnp    : int[NB*35]        @ 88064    per-loss-block npos partial
// snp    : int[NB]           @ 105984   per-image npos (k_topk)
// sums   : double[NB*3]      @ 106496   per-image {hn, pos_conf, loc} (k_topk)
// donecnt: int               @ 109568   zeroed by k_loss each iteration
// code   : int[NB*NP]        @ 109824
// confneg: float[NB*NP]      @ 4580608

// -------- wave64 reductions via DPP (VALU pipe); result uniform via readlane(63)
__device__ __forceinline__ float wave64_fmax_u(float m) {
    int v;
    v = __builtin_amdgcn_update_dpp(__float_as_int(m), __float_as_int(m), 0x111, 0xf, 0xf, false);
    m = fmaxf(m, __int_as_float(v));
    v = __builtin_amdgcn_update_dpp(__float_as_int(m), __float_as_int(m), 0x112, 0xf, 0xf, false);
    m = fmaxf(m, __int_as_float(v));
    v = __builtin_amdgcn_update_dpp(__float_as_int(m), __float_as_int(m), 0x114, 0xf, 0xf, false);
    m = fmaxf(m, __int_as_float(v));
    v = __builtin_amdgcn_update_dpp(__float_as_int(m), __float_as_int(m), 0x118, 0xf, 0xf, false);
    m = fmaxf(m, __int_as_float(v));
    v = __builtin_amdgcn_update_dpp(__float_as_int(m), __float_as_int(m), 0x142, 0xf, 0xf, false);
    m = fmaxf(m, __int_as_float(v));
    v = __builtin_amdgcn_update_dpp(__float_as_int(m), __float_as_int(m), 0x143, 0xf, 0xf, false);
    m = fmaxf(m, __int_as_float(v));
    return __int_as_float(__builtin_amdgcn_readlane(__float_as_int(m), 63));
}

__device__ __forceinline__ int wave64_imin_u(int m) {
    int v;
    v = __builtin_amdgcn_update_dpp(m, m, 0x111, 0xf, 0xf, false); m = v < m ? v : m;
    v = __builtin_amdgcn_update_dpp(m, m, 0x112, 0xf, 0xf, false); m = v < m ? v : m;
    v = __builtin_amdgcn_update_dpp(m, m, 0x114, 0xf, 0xf, false); m = v < m ? v : m;
    v = __builtin_amdgcn_update_dpp(m, m, 0x118, 0xf, 0xf, false); m = v < m ? v : m;
    v = __builtin_amdgcn_update_dpp(m, m, 0x142, 0xf, 0xf, false); m = v < m ? v : m;
    v = __builtin_amdgcn_update_dpp(m, m, 0x143, 0xf, 0xf, false); m = v < m ? v : m;
    return __builtin_amdgcn_readlane(m, 63);
}

// Per-PRIOR argmax over 32 objects. Pure thread-local running max:
// no cross-lane ops, no atomics. 2 priors/thread, grid (18,128).
__global__ __launch_bounds__(256) void k_code(const float* __restrict__ boxes,
                                              const float* __restrict__ priors,
                                              int* __restrict__ code) {
    int b = blockIdx.y;
    int tid = threadIdx.x;
    int base = blockIdx.x * 512 + tid;

    __shared__ float4 sbox[NO];
    if (tid < NO)
        sbox[tid] = ((const float4*)(boxes + (size_t)b * NO * 4))[tid];
    __syncthreads();

    float px1[2], py1[2], px2[2], py2[2], pa[2];
    float bestv[2];
    int   besto[2];
#pragma unroll
    for (int j = 0; j < 2; ++j) {
        int p = base + 256 * j;
        int pp = p < NP ? p : NP - 1;   // tail clamp; result discarded (guarded store)
        float4 pr = ((const float4*)priors)[pp];
        px1[j] = pr.x - pr.z * 0.5f; py1[j] = pr.y - pr.w * 0.5f;
        px2[j] = pr.x + pr.z * 0.5f; py2[j] = pr.y + pr.w * 0.5f;
        pa[j]  = (px2[j] - px1[j]) * (py2[j] - py1[j]);
        bestv[j] = -1.0f; besto[j] = 0;
    }

#pragma unroll
    for (int o = 0; o < NO; ++o) {
        float4 bx = sbox[o];
        float a1 = (bx.z - bx.x) * (bx.w - bx.y);
#pragma unroll
        for (int j = 0; j < 2; ++j) {
            float lx = fmaxf(bx.x, px1[j]), ly = fmaxf(bx.y, py1[j]);
            float hx = fminf(bx.z, px2[j]), hy = fminf(bx.w, py2[j]);
            float iw = fmaxf(hx - lx, 0.0f), ih = fmaxf(hy - ly, 0.0f);
            float inter = iw * ih;
            float iou = inter / (a1 + pa[j] - inter);  // same expr/order as reference
            if (iou > bestv[j]) { bestv[j] = iou; besto[j] = o; }  // first max wins
        }
    }
#pragma unroll
    for (int j = 0; j < 2; ++j) {
        int p = base + 256 * j;
        if (p < NP)
            code[(size_t)b * NP + p] = besto[j] | (bestv[j] >= 0.5f ? 256 : 0);
    }
}

// Per-(b,o) argmax over all priors. One wave per (b,o): 137 independent
// IoUs/lane (perfect ILP), then ONE DPP max + masked DPP min-p per wave.
// Plain store -> no atomics, no init. grid (8,128), 4 waves/block (o = bx*4+wid).
__global__ __launch_bounds__(256) void k_obj(const float* __restrict__ boxes,
                                             const float* __restrict__ priors,
                                             int* __restrict__ pfor) {
    int b = blockIdx.y;
    int wid = threadIdx.x >> 6, lane = threadIdx.x & 63;
    int o = blockIdx.x * 4 + wid;

    float4 bx = ((const float4*)boxes)[b * NO + o];
    float a1 = (bx.z - bx.x) * (bx.w - bx.y);
    const float4* pr4 = (const float4*)priors;

    float bv = -1.0f; int bp = 0;
    for (int i = 0; i < 136; ++i) {      // p = lane + 64*i <= 8703, all valid
        int p = lane + (i << 6);
        float4 pr = pr4[p];
        float x1 = pr.x - pr.z * 0.5f, y1 = pr.y - pr.w * 0.5f;
        float x2 = pr.x + pr.z * 0.5f, y2 = pr.y + pr.w * 0.5f;
        float pa = (x2 - x1) * (y2 - y1);
        float lx = fmaxf(bx.x, x1), ly = fmaxf(bx.y, y1);
        float hx = fminf(bx.z, x2), hy = fminf(bx.w, y2);
        float inter = fmaxf(hx - lx, 0.0f) * fmaxf(hy - ly, 0.0f);
        float iou = inter / (a1 + pa - inter);
        if (iou > bv) { bv = iou; bp = p; }   // strict >, ascending p: per-lane first max
    }
    {   // tail: p = lane + 8704, valid for lane < 28
        int p = lane + 8704;
        if (p < NP) {
            float4 pr = pr4[p];
            float x1 = pr.x - pr.z * 0.5f, y1 = pr.y - pr.w * 0.5f;
            float x2 = pr.x + pr.z * 0.5f, y2 = pr.y + pr.w * 0.5f;
            float pa = (x2 - x1) * (y2 - y1);
            float lx = fmaxf(bx.x, x1), ly = fmaxf(bx.y, y1);
            float hx = fminf(bx.z, x2), hy = fminf(bx.w, y2);
            float inter = fmaxf(hx - lx, 0.0f) * fmaxf(hy - ly, 0.0f);
            float iou = inter / (a1 + pa - inter);
            if (iou > bv) { bv = iou; bp = p; }
        }
    }
    float m = wave64_fmax_u(bv);                    // exact wave max, uniform
    int pc = (bv == m) ? bp : 0x7FFFFFFF;           // ties: candidate = lane-local min-p
    int mp = wave64_imin_u(pc);                     // global min-p among ties
    if (lane == 0) pfor[b * NO + o] = mp;
}

// Scores staged through LDS with coalesced float4 loads. Forced matches via
// pfor broadcast compares (last o wins). Per-block PARTIAL sums (plain stores).
__global__ __launch_bounds__(256) void k_loss(const float* __restrict__ plocs,
                                              const float* __restrict__ scores,
                                              const float* __restrict__ boxes,
                                              const int* __restrict__ labels,
                                              const float* __restrict__ priors,
                                              const int* __restrict__ code,
                                              const int* __restrict__ pfor,
                                              float* __restrict__ confneg,
                                              int* __restrict__ pnp,
                                              double* __restrict__ pd0,
                                              double* __restrict__ pd1,
                                              int* __restrict__ donecnt) {
    __shared__ float srow[256 * NC];  // 21504 B
    __shared__ int spfl[NO];          // forced prior per object
    int b = blockIdx.y;
    int p0 = blockIdx.x * 256;
    int cnt = NP - p0; if (cnt > 256) cnt = 256;
    int nf4 = cnt * NC / 4;  // exact: 4 | cnt*21 for cnt in {256, 28}
    const float4* src4 = (const float4*)(scores + ((size_t)b * NP + p0) * NC);
    for (int i = threadIdx.x; i < nf4; i += 256)
        ((float4*)srow)[i] = src4[i];
    if (threadIdx.x < NO)
        spfl[threadIdx.x] = pfor[b * NO + threadIdx.x];
    __syncthreads();

    int p = p0 + threadIdx.x;
    float posconf = 0.0f, locpart = 0.0f;
    int isp = 0;

    if (p < NP) {
        int cd = code[(size_t)b * NP + p];
        int obj = cd & 255;
        int mat = cd >> 8;
#pragma unroll
        for (int o = 0; o < NO; ++o)
            if (spfl[o] == p) { obj = o; mat = 1; }  // last o wins (scatter semantics)
        int lbl = mat ? labels[b * NO + obj] : 0;

        const float* s = srow + threadIdx.x * NC;  // stride 21: bank-conflict-free
        float m = s[0];
#pragma unroll
        for (int c = 1; c < NC; ++c) m = fmaxf(m, s[c]);
        float sum = 0.0f;
#pragma unroll
        for (int c = 0; c < NC; ++c) sum += __expf(s[c] - m);
        float conf = m + __logf(sum) - s[lbl];

        if (lbl != 0) {
            isp = 1;
            posconf = conf;
            float4 bx = ((const float4*)boxes)[b * NO + obj];
            float4 pr = ((const float4*)priors)[p];
            float cx = (bx.x + bx.z) * 0.5f, cy = (bx.y + bx.w) * 0.5f;
            float w = bx.z - bx.x, h = bx.w - bx.y;
            float gx = (cx - pr.x) / (pr.z * 0.1f);
            float gy = (cy - pr.y) / (pr.w * 0.1f);
            float gw = __logf(w / pr.z) * 5.0f;
            float gh = __logf(h / pr.w) * 5.0f;
            float4 pl = ((const float4*)plocs)[(size_t)b * NP + p];
            locpart = fabsf(pl.x - gx) + fabsf(pl.y - gy) +
                      fabsf(pl.z - gw) + fabsf(pl.w - gh);
        }
        confneg[(size_t)b * NP + p] = isp ? 0.0f : conf;
    }

    // wave shuffle reduce, then 4-wave LDS combine, one barrier
    for (int s = 32; s > 0; s >>= 1) {
        posconf += __shfl_xor(posconf, s, 64);
        locpart += __shfl_xor(locpart, s, 64);
        isp     += __shfl_xor(isp, s, 64);
    }
    __shared__ float w0[4], w1[4];
    __shared__ int wc[4];
    int wid = threadIdx.x >> 6, lane = threadIdx.x & 63;
    if (lane == 0) { w0[wid] = posconf; w1[wid] = locpart; wc[wid] = isp; }
    __syncthreads();
    if (threadIdx.x == 0) {
        int pb = b * NCHUNK + blockIdx.x;
        pd0[pb] = (double)(w0[0] + w0[1] + w0[2] + w0[3]);
        pd1[pb] = (double)(w1[0] + w1[1] + w1[2] + w1[3]);
        pnp[pb] = wc[0] + wc[1] + wc[2] + wc[3];
        if (pb == 0) *donecnt = 0;   // stream-ordered before k_topk; poison-proof
    }
}

// Exact k-th-largest by bit bisection; one 256-thread block per image (barrier
// spans only 4 waves). Counting via ballot+popcount (wave-uniform, SALU).
// Last block (donecnt) does the final cross-image reduction.
__global__ __launch_bounds__(256) void k_topk(const float* __restrict__ confneg,
                                              const int* __restrict__ pnp,
                                              const double* __restrict__ pd0,
                                              const double* __restrict__ pd1,
                                              int* __restrict__ snp,
                                              double* __restrict__ sums,  // [NB][3] hn,pc,lc
                                              int* __restrict__ donecnt,
                                              float* __restrict__ out) {
    __shared__ int    si2[2][4];
    __shared__ int    siw[4];
    __shared__ double sdd[4];
    __shared__ int    sk;
    int tid = threadIdx.x, b = blockIdx.x;
    int lane = tid & 63, wid = tid >> 6;

    // prologue: wave 0 reduces the 35 per-chunk partials of image b
    if (wid == 0) {
        int np_ = 0; double d0 = 0.0, d1 = 0.0;
        if (lane < NCHUNK) {
            int pb = b * NCHUNK + lane;
            np_ = pnp[pb]; d0 = pd0[pb]; d1 = pd1[pb];
        }
        for (int s = 32; s > 0; s >>= 1) {
            np_ += __shfl_xor(np_, s, 64);
            d0  += __shfl_xor(d0, s, 64);
            d1  += __shfl_xor(d1, s, 64);
        }
        if (lane == 0) {
            int k = np_ * 3; if (k > NP) k = NP;
            sk = k;
            snp[b] = np_;
            sums[b * 3 + 1] = d0;
            sums[b * 3 + 2] = d1;
        }
    }

    const float* src = confneg + (size_t)b * NP;
    float val[35];
#pragma unroll
    for (int j = 0; j < 35; ++j) {
        int i = tid + j * 256;
        val[j] = (i < NP) ? src[i] : 0.0f;  // 0 never counts (cand>0)
    }
    __syncthreads();
    int k = sk;

    double hn = 0.0;
    if (k > 0) {   // block-uniform
        unsigned T = 0;
        int par = 0;
        for (int bit = 30; bit >= 0; --bit) {
            unsigned cand = T | (1u << bit);
            int cnt = 0;
#pragma unroll
            for (int j = 0; j < 35; ++j)
                cnt += __popcll(__ballot(__float_as_uint(val[j]) >= cand));  // wave-uniform
            if (lane == 0) si2[par][wid] = cnt;
            __syncthreads();
            int t = si2[par][0] + si2[par][1] + si2[par][2] + si2[par][3];
            par ^= 1;              // next write other buffer: no 2nd barrier
            if (t >= k) T = cand;  // uniform decision
        }

        int cgt = 0;
        double sgt = 0.0;
#pragma unroll
        for (int j = 0; j < 35; ++j) {
            unsigned u = __float_as_uint(val[j]);
            if (u > T) { cgt++; sgt += (double)val[j]; }
        }
        for (int s = 32; s > 0; s >>= 1) {
            cgt += __shfl_xor(cgt, s, 64);
            sgt += __shfl_xor(sgt, s, 64);
        }
        if (lane == 0) { siw[wid] = cgt; sdd[wid] = sgt; }
        __syncthreads();
        if (tid == 0) {
            int cg = siw[0] + siw[1] + siw[2] + siw[3];
            double sg = sdd[0] + sdd[1] + sdd[2] + sdd[3];
            hn = sg + (double)(k - cg) * (double)__uint_as_float(T);
        }
    }
    if (tid == 0) sums[b * 3 + 0] = hn;  // explicit 0 when k<=0 (overwrite poison)

    // ---- last-block final reduction ----
    __shared__ int samlast;
    if (tid == 0) {
        __threadfence();                   // sums/snp stores visible device-wide
        int prev = atomicAdd(donecnt, 1);  // device-scope
        samlast = (prev == NB - 1) ? 1 : 0;
    }
    __syncthreads();
    if (!samlast) return;
    __threadfence();

    double hnn = 0.0, pc = 0.0, lc = 0.0, npd = 0.0;
    if (tid < NB) {   // peer-written: atomic reads to dodge stale caches
        hnn = atomicAdd(&sums[tid * 3 + 0], 0.0);
        pc  = atomicAdd(&sums[tid * 3 + 1], 0.0);
        lc  = atomicAdd(&sums[tid * 3 + 2], 0.0);
        npd = (double)atomicAdd((int*)&snp[tid], 0);
    }
    for (int s = 32; s > 0; s >>= 1) {
        hnn += __shfl_xor(hnn, s, 64);
        pc  += __shfl_xor(pc, s, 64);
        lc  += __shfl_xor(lc, s, 64);
        npd += __shfl_xor(npd, s, 64);
    }
    __shared__ double sfin[4][2];
    if (lane == 0 && wid < 2) {
        sfin[0][wid] = hnn; sfin[1][wid] = pc; sfin[2][wid] = lc; sfin[3][wid] = npd;
    }
    __syncthreads();
    if (tid == 0) {
        double H  = sfin[0][0] + sfin[0][1];
        double P  = sfin[1][0] + sfin[1][1];
        double L  = sfin[2][0] + sfin[2][1];
        double nt = sfin[3][0] + sfin[3][1];
        out[0] = (float)((H + P) / nt + L / (nt * 4.0));
    }
}

extern "C" void kernel_launch(void* const* d_in, const int* in_sizes, int n_in,
                              void* d_out, int out_size, void* d_ws, size_t ws_size,
                              hipStream_t stream) {
    const float* plocs  = (const float*)d_in[0];
    const float* scores = (const float*)d_in[1];
    const float* boxes  = (const float*)d_in[2];
    const int*   labels = (const int*)d_in[3];
    const float* priors = (const float*)d_in[4];
    float* out = (float*)d_out;

    char* ws = (char*)d_ws;
    int*    pfor    = (int*)ws;
    double* pd0     = (double*)(ws + 16384);
    double* pd1     = (double*)(ws + 52224);
    int*    pnp     = (int*)(ws + 88064);
    int*    snp     = (int*)(ws + 105984);
    double* sums    = (double*)(ws + 106496);
    int*    donecnt = (int*)(ws + 109568);
    int*    code    = (int*)(ws + 109824);
    float*  confneg = (float*)(ws + 4580608);

    hipLaunchKernelGGL(k_code, dim3((NP + 511) / 512, NB), dim3(256), 0, stream,
                       boxes, priors, code);
    hipLaunchKernelGGL(k_obj, dim3(NO / 4, NB), dim3(256), 0, stream,
                       boxes, priors, pfor);
    hipLaunchKernelGGL(k_loss, dim3(NCHUNK, NB), dim3(256), 0, stream,
                       plocs, scores, boxes, labels, priors, code, pfor,
                       confneg, pnp, pd0, pd1, donecnt);
    hipLaunchKernelGGL(k_topk, dim3(NB), dim3(256), 0, stream,
                       confneg, pnp, pd0, pd1, snp, sums, donecnt, out);
}

// Round 5
// 227.624 us; speedup vs baseline: 1.0547x; 1.0547x over previous
//
#include <hip/hip_runtime.h>
#include <hip/hip_bf16.h>

#define NB 128
#define NP 8732
#define NO 32
#define NC 21
#define NCHUNK 35   // k_loss grid.x

// ---------------- workspace layout (no zero-init required anywhere) ----------
// pfor   : int[NB*NO]        @ 0        per-(b,o) argmax prior (plain store)
// pd0    : double[NB*35]     @ 16384    per-loss-block pos_conf partial
// pd1    : double[NB*35]     @ 52224    per-loss-block loc partial
// pnp    : int[NB*35]        @ 88064    per-loss-block npos partial
// snp    : int[NB]           @ 105984   per-image npos (k_topk)
// sums   : double[NB*3]      @ 106496   per-image {hn, pos_conf, loc} (k_topk)
// donecnt: int               @ 109568   zeroed by k_loss block pb==0
// confneg: float[NB*NP]      @ 109824

// -------- wave64 reductions via DPP (VALU pipe); result uniform via readlane(63)
__device__ __forceinline__ float wave64_fmax_u(float m) {
    int v;
    v = __builtin_amdgcn_update_dpp(__float_as_int(m), __float_as_int(m), 0x111, 0xf, 0xf, false);
    m = fmaxf(m, __int_as_float(v));
    v = __builtin_amdgcn_update_dpp(__float_as_int(m), __float_as_int(m), 0x112, 0xf, 0xf, false);
    m = fmaxf(m, __int_as_float(v));
    v = __builtin_amdgcn_update_dpp(__float_as_int(m), __float_as_int(m), 0x114, 0xf, 0xf, false);
    m = fmaxf(m, __int_as_float(v));
    v = __builtin_amdgcn_update_dpp(__float_as_int(m), __float_as_int(m), 0x118, 0xf, 0xf, false);
    m = fmaxf(m, __int_as_float(v));
    v = __builtin_amdgcn_update_dpp(__float_as_int(m), __float_as_int(m), 0x142, 0xf, 0xf, false);
    m = fmaxf(m, __int_as_float(v));
    v = __builtin_amdgcn_update_dpp(__float_as_int(m), __float_as_int(m), 0x143, 0xf, 0xf, false);
    m = fmaxf(m, __int_as_float(v));
    return __int_as_float(__builtin_amdgcn_readlane(__float_as_int(m), 63));
}

__device__ __forceinline__ int wave64_imin_u(int m) {
    int v;
    v = __builtin_amdgcn_update_dpp(m, m, 0x111, 0xf, 0xf, false); m = v < m ? v : m;
    v = __builtin_amdgcn_update_dpp(m, m, 0x112, 0xf, 0xf, false); m = v < m ? v : m;
    v = __builtin_amdgcn_update_dpp(m, m, 0x114, 0xf, 0xf, false); m = v < m ? v : m;
    v = __builtin_amdgcn_update_dpp(m, m, 0x118, 0xf, 0xf, false); m = v < m ? v : m;
    v = __builtin_amdgcn_update_dpp(m, m, 0x142, 0xf, 0xf, false); m = v < m ? v : m;
    v = __builtin_amdgcn_update_dpp(m, m, 0x143, 0xf, 0xf, false); m = v < m ? v : m;
    return __builtin_amdgcn_readlane(m, 63);
}

// Per-(b,o) argmax over all priors, LDS-shared priors.
// grid (4,NB), 256 threads: block stages priors in 16KB chunks ONCE; its 4
// waves each own 2 objects (8 objects/block). L2 prior traffic 570->71 MB.
// Per-lane p ascending + strict '>' => lane-local first-max; DPP max + masked
// DPP min-p => exact global argmax (first max). Plain store, no atomics/init.
__global__ __launch_bounds__(256) void k_obj(const float* __restrict__ boxes,
                                             const float* __restrict__ priors,
                                             int* __restrict__ pfor) {
    __shared__ float4 spr[1024];   // 16 KB chunk
    int b = blockIdx.y;
    int tid = threadIdx.x, lane = tid & 63, wid = tid >> 6;
    int o0 = blockIdx.x * 8 + wid * 2;

    float4 bx0 = ((const float4*)boxes)[b * NO + o0];
    float4 bx1 = ((const float4*)boxes)[b * NO + o0 + 1];
    float a10 = (bx0.z - bx0.x) * (bx0.w - bx0.y);
    float a11 = (bx1.z - bx1.x) * (bx1.w - bx1.y);

    float bv0 = -1.0f, bv1 = -1.0f;
    int   bp0 = 0,     bp1 = 0;

    for (int c0 = 0; c0 < NP; c0 += 1024) {
        int n = NP - c0; if (n > 1024) n = 1024;
        __syncthreads();   // protect buffer reuse
        for (int i = tid; i < n; i += 256)
            spr[i] = ((const float4*)priors)[c0 + i];
        __syncthreads();
#pragma unroll 4
        for (int i = lane; i < n; i += 64) {
            float4 pr = spr[i];
            float x1 = pr.x - pr.z * 0.5f, y1 = pr.y - pr.w * 0.5f;
            float x2 = pr.x + pr.z * 0.5f, y2 = pr.y + pr.w * 0.5f;
            float pa = (x2 - x1) * (y2 - y1);
            int p = c0 + i;
            {
                float lx = fmaxf(bx0.x, x1), ly = fmaxf(bx0.y, y1);
                float hx = fminf(bx0.z, x2), hy = fminf(bx0.w, y2);
                float inter = fmaxf(hx - lx, 0.0f) * fmaxf(hy - ly, 0.0f);
                float iou = inter / (a10 + pa - inter);  // same expr/order as reference
                if (iou > bv0) { bv0 = iou; bp0 = p; }
            }
            {
                float lx = fmaxf(bx1.x, x1), ly = fmaxf(bx1.y, y1);
                float hx = fminf(bx1.z, x2), hy = fminf(bx1.w, y2);
                float inter = fmaxf(hx - lx, 0.0f) * fmaxf(hy - ly, 0.0f);
                float iou = inter / (a11 + pa - inter);
                if (iou > bv1) { bv1 = iou; bp1 = p; }
            }
        }
    }
    float m0 = wave64_fmax_u(bv0);
    int mp0 = wave64_imin_u((bv0 == m0) ? bp0 : 0x7FFFFFFF);
    float m1 = wave64_fmax_u(bv1);
    int mp1 = wave64_imin_u((bv1 == m1) ? bp1 : 0x7FFFFFFF);
    if (lane == 0) {
        pfor[b * NO + o0]     = mp0;
        pfor[b * NO + o0 + 1] = mp1;
    }
}

// Scores staged through LDS with coalesced float4 loads. Per-prior argmax over
// the 32 objects INLINED (sbox broadcast reads; no code[] round-trip). Forced
// matches via pfor broadcast compares (last o wins). Per-block PARTIAL sums.
__global__ __launch_bounds__(256) void k_loss(const float* __restrict__ plocs,
                                              const float* __restrict__ scores,
                                              const float* __restrict__ boxes,
                                              const int* __restrict__ labels,
                                              const float* __restrict__ priors,
                                              const int* __restrict__ pfor,
                                              float* __restrict__ confneg,
                                              int* __restrict__ pnp,
                                              double* __restrict__ pd0,
                                              double* __restrict__ pd1,
                                              int* __restrict__ donecnt) {
    __shared__ float srow[256 * NC];  // 21504 B
    __shared__ float4 sbox[NO];       // 512 B
    __shared__ int spfl[NO];          // forced prior per object
    int b = blockIdx.y;
    int p0 = blockIdx.x * 256;
    int cnt = NP - p0; if (cnt > 256) cnt = 256;
    int nf4 = cnt * NC / 4;  // exact: 4 | cnt*21 for cnt in {256, 28}
    const float4* src4 = (const float4*)(scores + ((size_t)b * NP + p0) * NC);
    for (int i = threadIdx.x; i < nf4; i += 256)
        ((float4*)srow)[i] = src4[i];
    if (threadIdx.x < NO) {
        sbox[threadIdx.x] = ((const float4*)boxes)[b * NO + threadIdx.x];
        spfl[threadIdx.x] = pfor[b * NO + threadIdx.x];
    }
    __syncthreads();

    int p = p0 + threadIdx.x;
    float posconf = 0.0f, locpart = 0.0f;
    int isp = 0;

    if (p < NP) {
        float4 pr = ((const float4*)priors)[p];
        float px1 = pr.x - pr.z * 0.5f, py1 = pr.y - pr.w * 0.5f;
        float px2 = pr.x + pr.z * 0.5f, py2 = pr.y + pr.w * 0.5f;
        float pa  = (px2 - px1) * (py2 - py1);

        // inline per-prior argmax over 32 objects (sbox reads are broadcasts)
        float bestv = -1.0f; int besto = 0;
#pragma unroll
        for (int o = 0; o < NO; ++o) {
            float4 bx = sbox[o];
            float a1 = (bx.z - bx.x) * (bx.w - bx.y);
            float lx = fmaxf(bx.x, px1), ly = fmaxf(bx.y, py1);
            float hx = fminf(bx.z, px2), hy = fminf(bx.w, py2);
            float inter = fmaxf(hx - lx, 0.0f) * fmaxf(hy - ly, 0.0f);
            float iou = inter / (a1 + pa - inter);  // same expr/order as reference
            if (iou > bestv) { bestv = iou; besto = o; }  // first max wins
        }
        int obj = besto;
        int mat = bestv >= 0.5f ? 1 : 0;
#pragma unroll
        for (int o = 0; o < NO; ++o)
            if (spfl[o] == p) { obj = o; mat = 1; }  // last o wins (scatter semantics)
        int lbl = mat ? labels[b * NO + obj] : 0;

        const float* s = srow + threadIdx.x * NC;  // stride 21: bank-conflict-free
        float m = s[0];
#pragma unroll
        for (int c = 1; c < NC; ++c) m = fmaxf(m, s[c]);
        float sum = 0.0f;
#pragma unroll
        for (int c = 0; c < NC; ++c) sum += __expf(s[c] - m);
        float conf = m + __logf(sum) - s[lbl];

        if (lbl != 0) {
            isp = 1;
            posconf = conf;
            float4 bx = sbox[obj];
            float cx = (bx.x + bx.z) * 0.5f, cy = (bx.y + bx.w) * 0.5f;
            float w = bx.z - bx.x, h = bx.w - bx.y;
            float gx = (cx - pr.x) / (pr.z * 0.1f);
            float gy = (cy - pr.y) / (pr.w * 0.1f);
            float gw = __logf(w / pr.z) * 5.0f;
            float gh = __logf(h / pr.w) * 5.0f;
            float4 pl = ((const float4*)plocs)[(size_t)b * NP + p];
            locpart = fabsf(pl.x - gx) + fabsf(pl.y - gy) +
                      fabsf(pl.z - gw) + fabsf(pl.w - gh);
        }
        confneg[(size_t)b * NP + p] = isp ? 0.0f : conf;
    }

    // wave shuffle reduce, then 4-wave LDS combine, one barrier
    for (int s = 32; s > 0; s >>= 1) {
        posconf += __shfl_xor(posconf, s, 64);
        locpart += __shfl_xor(locpart, s, 64);
        isp     += __shfl_xor(isp, s, 64);
    }
    __shared__ float w0[4], w1[4];
    __shared__ int wc[4];
    int wid = threadIdx.x >> 6, lane = threadIdx.x & 63;
    if (lane == 0) { w0[wid] = posconf; w1[wid] = locpart; wc[wid] = isp; }
    __syncthreads();
    if (threadIdx.x == 0) {
        int pb = b * NCHUNK + blockIdx.x;
        pd0[pb] = (double)(w0[0] + w0[1] + w0[2] + w0[3]);
        pd1[pb] = (double)(w1[0] + w1[1] + w1[2] + w1[3]);
        pnp[pb] = wc[0] + wc[1] + wc[2] + wc[3];
        if (pb == 0) *donecnt = 0;   // stream-ordered before k_topk; poison-proof
    }
}

// Exact k-th-largest by bit bisection; one 1024-thread block per image.
// Counting via ballot+popcount (wave-uniform); per-wave counts double-buffered
// (parity) -> ONE barrier per bisection step. Prologue reduces the 35 per-chunk
// partials. Last block (donecnt) does the final cross-image reduction.
__global__ __launch_bounds__(1024) void k_topk(const float* __restrict__ confneg,
                                               const int* __restrict__ pnp,
                                               const double* __restrict__ pd0,
                                               const double* __restrict__ pd1,
                                               int* __restrict__ snp,
                                               double* __restrict__ sums,  // [NB][3] hn,pc,lc
                                               int* __restrict__ donecnt,
                                               float* __restrict__ out) {
    __shared__ int    si2[2][16];
    __shared__ int    siw[16];
    __shared__ double sdd[16];
    __shared__ int    sk;
    int tid = threadIdx.x, b = blockIdx.x;
    int lane = tid & 63, wid = tid >> 6;

    // prologue: wave 0 reduces the 35 per-chunk partials of image b
    if (wid == 0) {
        int np_ = 0; double d0 = 0.0, d1 = 0.0;
        if (lane < NCHUNK) {
            int pb = b * NCHUNK + lane;
            np_ = pnp[pb]; d0 = pd0[pb]; d1 = pd1[pb];
        }
        for (int s = 32; s > 0; s >>= 1) {
            np_ += __shfl_xor(np_, s, 64);
            d0  += __shfl_xor(d0, s, 64);
            d1  += __shfl_xor(d1, s, 64);
        }
        if (lane == 0) {
            int k = np_ * 3; if (k > NP) k = NP;
            sk = k;
            snp[b] = np_;
            sums[b * 3 + 1] = d0;
            sums[b * 3 + 2] = d1;
        }
    }

    const float* src = confneg + (size_t)b * NP;
    float val[9];
#pragma unroll
    for (int j = 0; j < 9; ++j) {
        int i = tid + j * 1024;
        val[j] = (i < NP) ? src[i] : 0.0f;  // 0 never counts (cand>0)
    }
    __syncthreads();
    int k = sk;

    double hn = 0.0;
    if (k > 0) {   // block-uniform
        unsigned T = 0;
        int par = 0;
        for (int bit = 30; bit >= 0; --bit) {
            unsigned cand = T | (1u << bit);
            int cnt = 0;
#pragma unroll
            for (int j = 0; j < 9; ++j)
                cnt += __popcll(__ballot(__float_as_uint(val[j]) >= cand));  // wave-uniform
            if (lane == 0) si2[par][wid] = cnt;
            __syncthreads();
            int t = 0;
#pragma unroll
            for (int w = 0; w < 16; ++w) t += si2[par][w];
            par ^= 1;              // next write other buffer: no 2nd barrier
            if (t >= k) T = cand;  // uniform decision
        }

        int cgt = 0;
        double sgt = 0.0;
#pragma unroll
        for (int j = 0; j < 9; ++j) {
            unsigned u = __float_as_uint(val[j]);
            if (u > T) { cgt++; sgt += (double)val[j]; }
        }
        for (int s = 32; s > 0; s >>= 1) {
            cgt += __shfl_xor(cgt, s, 64);
            sgt += __shfl_xor(sgt, s, 64);
        }
        if (lane == 0) { siw[wid] = cgt; sdd[wid] = sgt; }
        __syncthreads();
        if (tid == 0) {
            int cg = 0; double sg = 0.0;
            for (int w = 0; w < 16; ++w) { cg += siw[w]; sg += sdd[w]; }
            hn = sg + (double)(k - cg) * (double)__uint_as_float(T);
        }
    }
    if (tid == 0) sums[b * 3 + 0] = hn;  // explicit 0 when k<=0 (overwrite poison)

    // ---- last-block final reduction ----
    __shared__ int samlast;
    if (tid == 0) {
        __threadfence();                   // sums/snp stores visible device-wide
        int prev = atomicAdd(donecnt, 1);  // device-scope
        samlast = (prev == NB - 1) ? 1 : 0;
    }
    __syncthreads();
    if (!samlast) return;
    __threadfence();

    double hnn = 0.0, pc = 0.0, lc = 0.0, npd = 0.0;
    if (tid < NB) {   // peer-written: atomic reads to dodge stale caches
        hnn = atomicAdd(&sums[tid * 3 + 0], 0.0);
        pc  = atomicAdd(&sums[tid * 3 + 1], 0.0);
        lc  = atomicAdd(&sums[tid * 3 + 2], 0.0);
        npd = (double)atomicAdd((int*)&snp[tid], 0);
    }
    for (int s = 32; s > 0; s >>= 1) {
        hnn += __shfl_xor(hnn, s, 64);
        pc  += __shfl_xor(pc, s, 64);
        lc  += __shfl_xor(lc, s, 64);
        npd += __shfl_xor(npd, s, 64);
    }
    __shared__ double sfin[4][2];
    if (lane == 0 && wid < 2) {
        sfin[0][wid] = hnn; sfin[1][wid] = pc; sfin[2][wid] = lc; sfin[3][wid] = npd;
    }
    __syncthreads();
    if (tid == 0) {
        double H  = sfin[0][0] + sfin[0][1];
        double P  = sfin[1][0] + sfin[1][1];
        double L  = sfin[2][0] + sfin[2][1];
        double nt = sfin[3][0] + sfin[3][1];
        out[0] = (float)((H + P) / nt + L / (nt * 4.0));
    }
}

extern "C" void kernel_launch(void* const* d_in, const int* in_sizes, int n_in,
                              void* d_out, int out_size, void* d_ws, size_t ws_size,
                              hipStream_t stream) {
    const float* plocs  = (const float*)d_in[0];
    const float* scores = (const float*)d_in[1];
    const float* boxes  = (const float*)d_in[2];
    const int*   labels = (const int*)d_in[3];
    const float* priors = (const float*)d_in[4];
    float* out = (float*)d_out;

    char* ws = (char*)d_ws;
    int*    pfor    = (int*)ws;
    double* pd0     = (double*)(ws + 16384);
    double* pd1     = (double*)(ws + 52224);
    int*    pnp     = (int*)(ws + 88064);
    int*    snp     = (int*)(ws + 105984);
    double* sums    = (double*)(ws + 106496);
    int*    donecnt = (int*)(ws + 109568);
    float*  confneg = (float*)(ws + 109824);

    hipLaunchKernelGGL(k_obj, dim3(NO / 8, NB), dim3(256), 0, stream,
                       boxes, priors, pfor);
    hipLaunchKernelGGL(k_loss, dim3(NCHUNK, NB), dim3(256), 0, stream,
                       plocs, scores, boxes, labels, priors, pfor,
                       confneg, pnp, pd0, pd1, donecnt);
    hipLaunchKernelGGL(k_topk, dim3(NB), dim3(1024), 0, stream,
                       confneg, pnp, pd0, pd1, snp, sums, donecnt, out);
}

// Round 6
// 225.027 us; speedup vs baseline: 1.0669x; 1.0115x over previous
//
#include <hip/hip_runtime.h>

#define NB 128
#define NP 8732
#define NO 32
#define NC 21
#define NCHUNK 35   // k_loss grid.x

// ---------------- workspace layout (no zero-init required anywhere) ----------
// pfor   : int[NB*NO]        @ 0        per-(b,o) argmax prior (plain store)
// pd0    : double[NB*35]     @ 16384    per-loss-block pos_conf partial
// pd1    : double[NB*35]     @ 52224    per-loss-block loc partial
// pnp    : int[NB*35]        @ 88064    per-loss-block npos partial
// snp    : int[NB]           @ 105984   per-image npos (k_topk)
// sums   : double[NB*3]      @ 106496   per-image {hn, pos_conf, loc} (k_topk)
// donecnt: int               @ 109568   zeroed by k_loss block pb==0
// confneg: float[NB*NP]      @ 109824

// -------- wave64 reductions via DPP (VALU pipe); result uniform via readlane(63)
__device__ __forceinline__ float wave64_fmax_u(float m) {
    int v;
    v = __builtin_amdgcn_update_dpp(__float_as_int(m), __float_as_int(m), 0x111, 0xf, 0xf, false);
    m = fmaxf(m, __int_as_float(v));
    v = __builtin_amdgcn_update_dpp(__float_as_int(m), __float_as_int(m), 0x112, 0xf, 0xf, false);
    m = fmaxf(m, __int_as_float(v));
    v = __builtin_amdgcn_update_dpp(__float_as_int(m), __float_as_int(m), 0x114, 0xf, 0xf, false);
    m = fmaxf(m, __int_as_float(v));
    v = __builtin_amdgcn_update_dpp(__float_as_int(m), __float_as_int(m), 0x118, 0xf, 0xf, false);
    m = fmaxf(m, __int_as_float(v));
    v = __builtin_amdgcn_update_dpp(__float_as_int(m), __float_as_int(m), 0x142, 0xf, 0xf, false);
    m = fmaxf(m, __int_as_float(v));
    v = __builtin_amdgcn_update_dpp(__float_as_int(m), __float_as_int(m), 0x143, 0xf, 0xf, false);
    m = fmaxf(m, __int_as_float(v));
    return __int_as_float(__builtin_amdgcn_readlane(__float_as_int(m), 63));
}

__device__ __forceinline__ int wave64_imin_u(int m) {
    int v;
    v = __builtin_amdgcn_update_dpp(m, m, 0x111, 0xf, 0xf, false); m = v < m ? v : m;
    v = __builtin_amdgcn_update_dpp(m, m, 0x112, 0xf, 0xf, false); m = v < m ? v : m;
    v = __builtin_amdgcn_update_dpp(m, m, 0x114, 0xf, 0xf, false); m = v < m ? v : m;
    v = __builtin_amdgcn_update_dpp(m, m, 0x118, 0xf, 0xf, false); m = v < m ? v : m;
    v = __builtin_amdgcn_update_dpp(m, m, 0x142, 0xf, 0xf, false); m = v < m ? v : m;
    v = __builtin_amdgcn_update_dpp(m, m, 0x143, 0xf, 0xf, false); m = v < m ? v : m;
    return __builtin_amdgcn_readlane(m, 63);
}

// Per-(b,o) argmax over all priors, LDS-shared priors. (unchanged from R5)
__global__ __launch_bounds__(256) void k_obj(const float* __restrict__ boxes,
                                             const float* __restrict__ priors,
                                             int* __restrict__ pfor) {
    __shared__ float4 spr[1024];   // 16 KB chunk
    int b = blockIdx.y;
    int tid = threadIdx.x, lane = tid & 63, wid = tid >> 6;
    int o0 = blockIdx.x * 8 + wid * 2;

    float4 bx0 = ((const float4*)boxes)[b * NO + o0];
    float4 bx1 = ((const float4*)boxes)[b * NO + o0 + 1];
    float a10 = (bx0.z - bx0.x) * (bx0.w - bx0.y);
    float a11 = (bx1.z - bx1.x) * (bx1.w - bx1.y);

    float bv0 = -1.0f, bv1 = -1.0f;
    int   bp0 = 0,     bp1 = 0;

    for (int c0 = 0; c0 < NP; c0 += 1024) {
        int n = NP - c0; if (n > 1024) n = 1024;
        __syncthreads();   // protect buffer reuse
        for (int i = tid; i < n; i += 256)
            spr[i] = ((const float4*)priors)[c0 + i];
        __syncthreads();
#pragma unroll 4
        for (int i = lane; i < n; i += 64) {
            float4 pr = spr[i];
            float x1 = pr.x - pr.z * 0.5f, y1 = pr.y - pr.w * 0.5f;
            float x2 = pr.x + pr.z * 0.5f, y2 = pr.y + pr.w * 0.5f;
            float pa = (x2 - x1) * (y2 - y1);
            int p = c0 + i;
            {
                float lx = fmaxf(bx0.x, x1), ly = fmaxf(bx0.y, y1);
                float hx = fminf(bx0.z, x2), hy = fminf(bx0.w, y2);
                float inter = fmaxf(hx - lx, 0.0f) * fmaxf(hy - ly, 0.0f);
                float iou = inter / (a10 + pa - inter);  // same expr/order as reference
                if (iou > bv0) { bv0 = iou; bp0 = p; }
            }
            {
                float lx = fmaxf(bx1.x, x1), ly = fmaxf(bx1.y, y1);
                float hx = fminf(bx1.z, x2), hy = fminf(bx1.w, y2);
                float inter = fmaxf(hx - lx, 0.0f) * fmaxf(hy - ly, 0.0f);
                float iou = inter / (a11 + pa - inter);
                if (iou > bv1) { bv1 = iou; bp1 = p; }
            }
        }
    }
    float m0 = wave64_fmax_u(bv0);
    int mp0 = wave64_imin_u((bv0 == m0) ? bp0 : 0x7FFFFFFF);
    float m1 = wave64_fmax_u(bv1);
    int mp1 = wave64_imin_u((bv1 == m1) ? bp1 : 0x7FFFFFFF);
    if (lane == 0) {
        pfor[b * NO + o0]     = mp0;
        pfor[b * NO + o0 + 1] = mp1;
    }
}

// Direct per-thread score-row loads (registers, no LDS staging/barrier).
// Forced-override via ballot-compacted per-block list (avg ~1.8 entries).
// Per-prior 32-object argmax inline; per-block PARTIAL sums (plain stores).
__global__ __launch_bounds__(256) void k_loss(const float* __restrict__ plocs,
                                              const float* __restrict__ scores,
                                              const float* __restrict__ boxes,
                                              const int* __restrict__ labels,
                                              const float* __restrict__ priors,
                                              const int* __restrict__ pfor,
                                              float* __restrict__ confneg,
                                              int* __restrict__ pnp,
                                              double* __restrict__ pd0,
                                              double* __restrict__ pd1,
                                              int* __restrict__ donecnt) {
    __shared__ float4 sbox[NO];
    __shared__ float  sa1[NO];
    __shared__ int    slbl[NO];
    __shared__ int    sfp[NO], sfo[NO];   // compacted forced list (o ascending)
    __shared__ int    snf;
    int b = blockIdx.y;
    int p0 = blockIdx.x * 256;
    int tid = threadIdx.x;

    if (tid < NO) {
        float4 bx = ((const float4*)boxes)[b * NO + tid];
        sbox[tid] = bx;
        sa1[tid]  = (bx.z - bx.x) * (bx.w - bx.y);
        slbl[tid] = labels[b * NO + tid];
    }
    if (tid < 64) {   // wave 0 builds the forced list for this 256-prior window
        int f = -1, inr = 0;
        if (tid < NO) {
            f = pfor[b * NO + tid];
            inr = (f >= p0) && (f < p0 + 256);
        }
        unsigned long long mask = __ballot(inr);
        if (inr) {
            int rank = __popcll(mask & ((1ull << tid) - 1));  // preserves o order
            sfp[rank] = f; sfo[rank] = tid;
        }
        if (tid == 0) snf = __popcll(mask);
    }
    __syncthreads();

    int p = p0 + tid;
    float posconf = 0.0f, locpart = 0.0f;
    int isp = 0;

    if (p < NP) {
        float4 pr = ((const float4*)priors)[p];
        float px1 = pr.x - pr.z * 0.5f, py1 = pr.y - pr.w * 0.5f;
        float px2 = pr.x + pr.z * 0.5f, py2 = pr.y + pr.w * 0.5f;
        float pa  = (px2 - px1) * (py2 - py1);

        // inline per-prior argmax over 32 objects (sbox/sa1 reads are broadcasts)
        float bestv = -1.0f; int besto = 0;
#pragma unroll
        for (int o = 0; o < NO; ++o) {
            float4 bx = sbox[o];
            float lx = fmaxf(bx.x, px1), ly = fmaxf(bx.y, py1);
            float hx = fminf(bx.z, px2), hy = fminf(bx.w, py2);
            float inter = fmaxf(hx - lx, 0.0f) * fmaxf(hy - ly, 0.0f);
            float iou = inter / (sa1[o] + pa - inter);  // same expr/order as reference
            if (iou > bestv) { bestv = iou; besto = o; }  // first max wins
        }
        int obj = besto;
        int mat = bestv >= 0.5f ? 1 : 0;
        int nf = snf;
        for (int i = 0; i < nf; ++i)              // usually 0-3 entries, o ascending
            if (sfp[i] == p) { obj = sfo[i]; mat = 1; }  // last o wins (scatter)
        int lbl = mat ? slbl[obj] : 0;

        // direct row load: 5x dwordx4 + 1 dword (dword-aligned; CDNA VMEM
        // multi-dword needs only 4B alignment), all 21 scores in registers
        const float* srow = scores + ((size_t)b * NP + p) * NC;
        const float4* r4 = (const float4*)srow;
        float4 q0 = r4[0], q1 = r4[1], q2 = r4[2], q3 = r4[3], q4 = r4[4];
        float s[NC] = {q0.x, q0.y, q0.z, q0.w, q1.x, q1.y, q1.z, q1.w,
                       q2.x, q2.y, q2.z, q2.w, q3.x, q3.y, q3.z, q3.w,
                       q4.x, q4.y, q4.z, q4.w, srow[20]};
        float m = s[0];
#pragma unroll
        for (int c = 1; c < NC; ++c) m = fmaxf(m, s[c]);
        float sum = 0.0f, sl = s[0];
#pragma unroll
        for (int c = 0; c < NC; ++c) {
            sum += __expf(s[c] - m);               // ascending c: same order as before
            if (c > 0) sl = (lbl == c) ? s[c] : sl;  // static-index extract of s[lbl]
        }
        float conf = m + __logf(sum) - sl;

        if (lbl != 0) {
            isp = 1;
            posconf = conf;
            float4 bx = sbox[obj];
            float cx = (bx.x + bx.z) * 0.5f, cy = (bx.y + bx.w) * 0.5f;
            float w = bx.z - bx.x, h = bx.w - bx.y;
            float gx = (cx - pr.x) / (pr.z * 0.1f);
            float gy = (cy - pr.y) / (pr.w * 0.1f);
            float gw = __logf(w / pr.z) * 5.0f;
            float gh = __logf(h / pr.w) * 5.0f;
            float4 pl = ((const float4*)plocs)[(size_t)b * NP + p];
            locpart = fabsf(pl.x - gx) + fabsf(pl.y - gy) +
                      fabsf(pl.z - gw) + fabsf(pl.w - gh);
        }
        confneg[(size_t)b * NP + p] = isp ? 0.0f : conf;
    }

    // wave shuffle reduce, then 4-wave LDS combine, one barrier
    for (int s = 32; s > 0; s >>= 1) {
        posconf += __shfl_xor(posconf, s, 64);
        locpart += __shfl_xor(locpart, s, 64);
        isp     += __shfl_xor(isp, s, 64);
    }
    __shared__ float w0[4], w1[4];
    __shared__ int wc[4];
    int wid = tid >> 6, lane = tid & 63;
    if (lane == 0) { w0[wid] = posconf; w1[wid] = locpart; wc[wid] = isp; }
    __syncthreads();
    if (tid == 0) {
        int pb = b * NCHUNK + blockIdx.x;
        pd0[pb] = (double)(w0[0] + w0[1] + w0[2] + w0[3]);
        pd1[pb] = (double)(w1[0] + w1[1] + w1[2] + w1[3]);
        pnp[pb] = wc[0] + wc[1] + wc[2] + wc[3];
        if (pb == 0) *donecnt = 0;   // stream-ordered before k_topk; poison-proof
    }
}

// Exact k-th-largest by bit bisection; one 1024-thread block per image.
// (unchanged from R5)
__global__ __launch_bounds__(1024) void k_topk(const float* __restrict__ confneg,
                                               const int* __restrict__ pnp,
                                               const double* __restrict__ pd0,
                                               const double* __restrict__ pd1,
                                               int* __restrict__ snp,
                                               double* __restrict__ sums,  // [NB][3] hn,pc,lc
                                               int* __restrict__ donecnt,
                                               float* __restrict__ out) {
    __shared__ int    si2[2][16];
    __shared__ int    siw[16];
    __shared__ double sdd[16];
    __shared__ int    sk;
    int tid = threadIdx.x, b = blockIdx.x;
    int lane = tid & 63, wid = tid >> 6;

    // prologue: wave 0 reduces the 35 per-chunk partials of image b
    if (wid == 0) {
        int np_ = 0; double d0 = 0.0, d1 = 0.0;
        if (lane < NCHUNK) {
            int pb = b * NCHUNK + lane;
            np_ = pnp[pb]; d0 = pd0[pb]; d1 = pd1[pb];
        }
        for (int s = 32; s > 0; s >>= 1) {
            np_ += __shfl_xor(np_, s, 64);
            d0  += __shfl_xor(d0, s, 64);
            d1  += __shfl_xor(d1, s, 64);
        }
        if (lane == 0) {
            int k = np_ * 3; if (k > NP) k = NP;
            sk = k;
            snp[b] = np_;
            sums[b * 3 + 1] = d0;
            sums[b * 3 + 2] = d1;
        }
    }

    const float* src = confneg + (size_t)b * NP;
    float val[9];
#pragma unroll
    for (int j = 0; j < 9; ++j) {
        int i = tid + j * 1024;
        val[j] = (i < NP) ? src[i] : 0.0f;  // 0 never counts (cand>0)
    }
    __syncthreads();
    int k = sk;

    double hn = 0.0;
    if (k > 0) {   // block-uniform
        unsigned T = 0;
        int par = 0;
        for (int bit = 30; bit >= 0; --bit) {
            unsigned cand = T | (1u << bit);
            int cnt = 0;
#pragma unroll
            for (int j = 0; j < 9; ++j)
                cnt += __popcll(__ballot(__float_as_uint(val[j]) >= cand));  // wave-uniform
            if (lane == 0) si2[par][wid] = cnt;
            __syncthreads();
            int t = 0;
#pragma unroll
            for (int w = 0; w < 16; ++w) t += si2[par][w];
            par ^= 1;              // next write other buffer: no 2nd barrier
            if (t >= k) T = cand;  // uniform decision
        }

        int cgt = 0;
        double sgt = 0.0;
#pragma unroll
        for (int j = 0; j < 9; ++j) {
            unsigned u = __float_as_uint(val[j]);
            if (u > T) { cgt++; sgt += (double)val[j]; }
        }
        for (int s = 32; s > 0; s >>= 1) {
            cgt += __shfl_xor(cgt, s, 64);
            sgt += __shfl_xor(sgt, s, 64);
        }
        if (lane == 0) { siw[wid] = cgt; sdd[wid] = sgt; }
        __syncthreads();
        if (tid == 0) {
            int cg = 0; double sg = 0.0;
            for (int w = 0; w < 16; ++w) { cg += siw[w]; sg += sdd[w]; }
            hn = sg + (double)(k - cg) * (double)__uint_as_float(T);
        }
    }
    if (tid == 0) sums[b * 3 + 0] = hn;  // explicit 0 when k<=0 (overwrite poison)

    // ---- last-block final reduction ----
    __shared__ int samlast;
    if (tid == 0) {
        __threadfence();                   // sums/snp stores visible device-wide
        int prev = atomicAdd(donecnt, 1);  // device-scope
        samlast = (prev == NB - 1) ? 1 : 0;
    }
    __syncthreads();
    if (!samlast) return;
    __threadfence();

    double hnn = 0.0, pc = 0.0, lc = 0.0, npd = 0.0;
    if (tid < NB) {   // peer-written: atomic reads to dodge stale caches
        hnn = atomicAdd(&sums[tid * 3 + 0], 0.0);
        pc  = atomicAdd(&sums[tid * 3 + 1], 0.0);
        lc  = atomicAdd(&sums[tid * 3 + 2], 0.0);
        npd = (double)atomicAdd((int*)&snp[tid], 0);
    }
    for (int s = 32; s > 0; s >>= 1) {
        hnn += __shfl_xor(hnn, s, 64);
        pc  += __shfl_xor(pc, s, 64);
        lc  += __shfl_xor(lc, s, 64);
        npd += __shfl_xor(npd, s, 64);
    }
    __shared__ double sfin[4][2];
    if (lane == 0 && wid < 2) {
        sfin[0][wid] = hnn; sfin[1][wid] = pc; sfin[2][wid] = lc; sfin[3][wid] = npd;
    }
    __syncthreads();
    if (tid == 0) {
        double H  = sfin[0][0] + sfin[0][1];
        double P  = sfin[1][0] + sfin[1][1];
        double L  = sfin[2][0] + sfin[2][1];
        double nt = sfin[3][0] + sfin[3][1];
        out[0] = (float)((H + P) / nt + L / (nt * 4.0));
    }
}

extern "C" void kernel_launch(void* const* d_in, const int* in_sizes, int n_in,
                              void* d_out, int out_size, void* d_ws, size_t ws_size,
                              hipStream_t stream) {
    const float* plocs  = (const float*)d_in[0];
    const float* scores = (const float*)d_in[1];
    const float* boxes  = (const float*)d_in[2];
    const int*   labels = (const int*)d_in[3];
    const float* priors = (const float*)d_in[4];
    float* out = (float*)d_out;

    char* ws = (char*)d_ws;
    int*    pfor    = (int*)ws;
    double* pd0     = (double*)(ws + 16384);
    double* pd1     = (double*)(ws + 52224);
    int*    pnp     = (int*)(ws + 88064);
    int*    snp     = (int*)(ws + 105984);
    double* sums    = (double*)(ws + 106496);
    int*    donecnt = (int*)(ws + 109568);
    float*  confneg = (float*)(ws + 109824);

    hipLaunchKernelGGL(k_obj, dim3(NO / 8, NB), dim3(256), 0, stream,
                       boxes, priors, pfor);
    hipLaunchKernelGGL(k_loss, dim3(NCHUNK, NB), dim3(256), 0, stream,
                       plocs, scores, boxes, labels, priors, pfor,
                       confneg, pnp, pd0, pd1, donecnt);
    hipLaunchKernelGGL(k_topk, dim3(NB), dim3(1024), 0, stream,
                       confneg, pnp, pd0, pd1, snp, sums, donecnt, out);
}

// Round 7
// 220.359 us; speedup vs baseline: 1.0895x; 1.0212x over previous
//
#include <hip/hip_runtime.h>

#define NB 128
#define NP 8732
#define NO 32
#define NC 21
#define NCHUNK 35   // k_loss grid.x

// ---------------- workspace layout (no zero-init required anywhere) ----------
// pfor   : int[NB*NO]        @ 0        per-(b,o) argmax prior (plain store)
// pd0    : double[NB*35]     @ 16384    per-loss-block pos_conf partial
// pd1    : double[NB*35]     @ 52224    per-loss-block loc partial
// pnp    : int[NB*35]        @ 88064    per-loss-block npos partial
// snp    : int[NB]           @ 105984   per-image npos (k_topk)
// sums   : double[NB*3]      @ 106496   per-image {hn, pos_conf, loc} (k_topk)
// donecnt: int               @ 109568   zeroed by k_loss block pb==0
// confneg: float[NB*NP]      @ 109824

// -------- wave64 reductions via DPP (VALU pipe); result uniform via readlane(63)
__device__ __forceinline__ float wave64_fmax_u(float m) {
    int v;
    v = __builtin_amdgcn_update_dpp(__float_as_int(m), __float_as_int(m), 0x111, 0xf, 0xf, false);
    m = fmaxf(m, __int_as_float(v));
    v = __builtin_amdgcn_update_dpp(__float_as_int(m), __float_as_int(m), 0x112, 0xf, 0xf, false);
    m = fmaxf(m, __int_as_float(v));
    v = __builtin_amdgcn_update_dpp(__float_as_int(m), __float_as_int(m), 0x114, 0xf, 0xf, false);
    m = fmaxf(m, __int_as_float(v));
    v = __builtin_amdgcn_update_dpp(__float_as_int(m), __float_as_int(m), 0x118, 0xf, 0xf, false);
    m = fmaxf(m, __int_as_float(v));
    v = __builtin_amdgcn_update_dpp(__float_as_int(m), __float_as_int(m), 0x142, 0xf, 0xf, false);
    m = fmaxf(m, __int_as_float(v));
    v = __builtin_amdgcn_update_dpp(__float_as_int(m), __float_as_int(m), 0x143, 0xf, 0xf, false);
    m = fmaxf(m, __int_as_float(v));
    return __int_as_float(__builtin_amdgcn_readlane(__float_as_int(m), 63));
}

__device__ __forceinline__ int wave64_imin_u(int m) {
    int v;
    v = __builtin_amdgcn_update_dpp(m, m, 0x111, 0xf, 0xf, false); m = v < m ? v : m;
    v = __builtin_amdgcn_update_dpp(m, m, 0x112, 0xf, 0xf, false); m = v < m ? v : m;
    v = __builtin_amdgcn_update_dpp(m, m, 0x114, 0xf, 0xf, false); m = v < m ? v : m;
    v = __builtin_amdgcn_update_dpp(m, m, 0x118, 0xf, 0xf, false); m = v < m ? v : m;
    v = __builtin_amdgcn_update_dpp(m, m, 0x142, 0xf, 0xf, false); m = v < m ? v : m;
    v = __builtin_amdgcn_update_dpp(m, m, 0x143, 0xf, 0xf, false); m = v < m ? v : m;
    return __builtin_amdgcn_readlane(m, 63);
}

// Per-(b,o) argmax over all priors. grid (8,NB): block owns 4 objects (boxes
// uniform -> SGPRs); thread scans p = tid + 256k (coalesced float4, one load
// feeds 4 independent IoU argmaxes). Per-wave DPP reduce per object, packed
// u64 partials in LDS, 4-entry combine. No staging barriers, no atomics.
__global__ __launch_bounds__(256) void k_obj(const float* __restrict__ boxes,
                                             const float* __restrict__ priors,
                                             int* __restrict__ pfor) {
    __shared__ unsigned long long part[4][4];   // [wave][object]
    int b = blockIdx.y;
    int tid = threadIdx.x, lane = tid & 63, wid = tid >> 6;
    int o0 = blockIdx.x * 4;

    float4 bx[4]; float a1[4];
#pragma unroll
    for (int i = 0; i < 4; ++i) {
        bx[i] = ((const float4*)boxes)[b * NO + o0 + i];   // uniform -> s_load
        a1[i] = (bx[i].z - bx[i].x) * (bx[i].w - bx[i].y);
    }

    float bv[4] = {-1.0f, -1.0f, -1.0f, -1.0f};
    int   bp[4] = {0, 0, 0, 0};
    const float4* pr4 = (const float4*)priors;

    for (int k = 0; k < 34; ++k) {               // p <= 255+8448 = 8703 < NP
        int p = tid + (k << 8);
        float4 pr = pr4[p];
        float x1 = pr.x - pr.z * 0.5f, y1 = pr.y - pr.w * 0.5f;
        float x2 = pr.x + pr.z * 0.5f, y2 = pr.y + pr.w * 0.5f;
        float pa = (x2 - x1) * (y2 - y1);
#pragma unroll
        for (int i = 0; i < 4; ++i) {
            float lx = fmaxf(bx[i].x, x1), ly = fmaxf(bx[i].y, y1);
            float hx = fminf(bx[i].z, x2), hy = fminf(bx[i].w, y2);
            float inter = fmaxf(hx - lx, 0.0f) * fmaxf(hy - ly, 0.0f);
            float iou = inter / (a1[i] + pa - inter);  // same expr/order as reference
            if (iou > bv[i]) { bv[i] = iou; bp[i] = p; }  // ascending p: first max
        }
    }
    {   // tail: p = tid + 8704, valid for tid < 28
        int p = tid + 8704;
        if (p < NP) {
            float4 pr = pr4[p];
            float x1 = pr.x - pr.z * 0.5f, y1 = pr.y - pr.w * 0.5f;
            float x2 = pr.x + pr.z * 0.5f, y2 = pr.y + pr.w * 0.5f;
            float pa = (x2 - x1) * (y2 - y1);
#pragma unroll
            for (int i = 0; i < 4; ++i) {
                float lx = fmaxf(bx[i].x, x1), ly = fmaxf(bx[i].y, y1);
                float hx = fminf(bx[i].z, x2), hy = fminf(bx[i].w, y2);
                float inter = fmaxf(hx - lx, 0.0f) * fmaxf(hy - ly, 0.0f);
                float iou = inter / (a1[i] + pa - inter);
                if (iou > bv[i]) { bv[i] = iou; bp[i] = p; }
            }
        }
    }

#pragma unroll
    for (int i = 0; i < 4; ++i) {
        float m = wave64_fmax_u(bv[i]);                      // exact wave max
        int mp = wave64_imin_u((bv[i] == m) ? bp[i] : 0x7FFFFFFF);  // min p @ max
        if (lane == 0)
            part[wid][i] = ((unsigned long long)__float_as_uint(m) << 32) |
                           (unsigned long long)(0xFFFFFFFFu - (unsigned)mp);
    }
    __syncthreads();
    if (tid < 4) {   // combine 4 wave-partials for object o0+tid
        unsigned long long best = part[0][tid];
        if (part[1][tid] > best) best = part[1][tid];
        if (part[2][tid] > best) best = part[2][tid];
        if (part[3][tid] > best) best = part[3][tid];
        pfor[b * NO + o0 + tid] = (int)(0xFFFFFFFFu - (unsigned)(best & 0xFFFFFFFFull));
    }
}

// Direct per-thread score-row loads, issued BEFORE the staging barrier (latency
// hidden under barrier + argmax). s[lbl] re-loaded from global (exact bits,
// replaces 20-deep cndmask chain). Forced-override via ballot-compacted list.
__global__ __launch_bounds__(256) void k_loss(const float* __restrict__ plocs,
                                              const float* __restrict__ scores,
                                              const float* __restrict__ boxes,
                                              const int* __restrict__ labels,
                                              const float* __restrict__ priors,
                                              const int* __restrict__ pfor,
                                              float* __restrict__ confneg,
                                              int* __restrict__ pnp,
                                              double* __restrict__ pd0,
                                              double* __restrict__ pd1,
                                              int* __restrict__ donecnt) {
    __shared__ float4 sbox[NO];
    __shared__ float  sa1[NO];
    __shared__ int    slbl[NO];
    __shared__ int    sfp[NO], sfo[NO];   // compacted forced list (o ascending)
    __shared__ int    snf;
    int b = blockIdx.y;
    int p0 = blockIdx.x * 256;
    int tid = threadIdx.x;
    int p = p0 + tid;
    bool valid = p < NP;

    // issue score-row loads early (independent of LDS staging)
    const float* srow = scores + ((size_t)b * NP + (valid ? p : NP - 1)) * NC;
    const float4* r4 = (const float4*)srow;
    float4 q0 = r4[0], q1 = r4[1], q2 = r4[2], q3 = r4[3], q4 = r4[4];
    float s20 = srow[20];

    if (tid < NO) {
        float4 bxx = ((const float4*)boxes)[b * NO + tid];
        sbox[tid] = bxx;
        sa1[tid]  = (bxx.z - bxx.x) * (bxx.w - bxx.y);
        slbl[tid] = labels[b * NO + tid];
    }
    if (tid < 64) {   // wave 0 builds the forced list for this 256-prior window
        int f = -1, inr = 0;
        if (tid < NO) {
            f = pfor[b * NO + tid];
            inr = (f >= p0) && (f < p0 + 256);
        }
        unsigned long long mask = __ballot(inr);
        if (inr) {
            int rank = __popcll(mask & ((1ull << tid) - 1));  // preserves o order
            sfp[rank] = f; sfo[rank] = tid;
        }
        if (tid == 0) snf = __popcll(mask);
    }
    __syncthreads();

    float posconf = 0.0f, locpart = 0.0f;
    int isp = 0;

    if (valid) {
        float4 pr = ((const float4*)priors)[p];
        float px1 = pr.x - pr.z * 0.5f, py1 = pr.y - pr.w * 0.5f;
        float px2 = pr.x + pr.z * 0.5f, py2 = pr.y + pr.w * 0.5f;
        float pa  = (px2 - px1) * (py2 - py1);

        // inline per-prior argmax over 32 objects (sbox/sa1 reads are broadcasts)
        float bestv = -1.0f; int besto = 0;
#pragma unroll
        for (int o = 0; o < NO; ++o) {
            float4 bxx = sbox[o];
            float lx = fmaxf(bxx.x, px1), ly = fmaxf(bxx.y, py1);
            float hx = fminf(bxx.z, px2), hy = fminf(bxx.w, py2);
            float inter = fmaxf(hx - lx, 0.0f) * fmaxf(hy - ly, 0.0f);
            float iou = inter / (sa1[o] + pa - inter);  // same expr/order as reference
            if (iou > bestv) { bestv = iou; besto = o; }  // first max wins
        }
        int obj = besto;
        int mat = bestv >= 0.5f ? 1 : 0;
        int nf = snf;
        for (int i = 0; i < nf; ++i)              // usually 0-3 entries, o ascending
            if (sfp[i] == p) { obj = sfo[i]; mat = 1; }  // last o wins (scatter)
        int lbl = mat ? slbl[obj] : 0;

        float sl = srow[lbl];   // one scatter dword; exact same bits as s[lbl]

        float s[NC] = {q0.x, q0.y, q0.z, q0.w, q1.x, q1.y, q1.z, q1.w,
                       q2.x, q2.y, q2.z, q2.w, q3.x, q3.y, q3.z, q3.w,
                       q4.x, q4.y, q4.z, q4.w, s20};
        float m = s[0];
#pragma unroll
        for (int c = 1; c < NC; ++c) m = fmaxf(m, s[c]);
        float sum = 0.0f;
#pragma unroll
        for (int c = 0; c < NC; ++c) sum += __expf(s[c] - m);  // ascending c order
        float conf = m + __logf(sum) - sl;

        if (lbl != 0) {
            isp = 1;
            posconf = conf;
            float4 bxx = sbox[obj];
            float cx = (bxx.x + bxx.z) * 0.5f, cy = (bxx.y + bxx.w) * 0.5f;
            float w = bxx.z - bxx.x, h = bxx.w - bxx.y;
            float gx = (cx - pr.x) / (pr.z * 0.1f);
            float gy = (cy - pr.y) / (pr.w * 0.1f);
            float gw = __logf(w / pr.z) * 5.0f;
            float gh = __logf(h / pr.w) * 5.0f;
            float4 pl = ((const float4*)plocs)[(size_t)b * NP + p];
            locpart = fabsf(pl.x - gx) + fabsf(pl.y - gy) +
                      fabsf(pl.z - gw) + fabsf(pl.w - gh);
        }
        confneg[(size_t)b * NP + p] = isp ? 0.0f : conf;
    }

    // wave shuffle reduce, then 4-wave LDS combine, one barrier
    for (int s = 32; s > 0; s >>= 1) {
        posconf += __shfl_xor(posconf, s, 64);
        locpart += __shfl_xor(locpart, s, 64);
        isp     += __shfl_xor(isp, s, 64);
    }
    __shared__ float w0[4], w1[4];
    __shared__ int wc[4];
    int wid = tid >> 6, lane = tid & 63;
    if (lane == 0) { w0[wid] = posconf; w1[wid] = locpart; wc[wid] = isp; }
    __syncthreads();
    if (tid == 0) {
        int pb = b * NCHUNK + blockIdx.x;
        pd0[pb] = (double)(w0[0] + w0[1] + w0[2] + w0[3]);
        pd1[pb] = (double)(w1[0] + w1[1] + w1[2] + w1[3]);
        pnp[pb] = wc[0] + wc[1] + wc[2] + wc[3];
        if (pb == 0) *donecnt = 0;   // stream-ordered before k_topk; poison-proof
    }
}

// Exact k-th-largest, radix-4 bit bisection: 16 barrier steps (bit 30, then 15
// dual-bit steps; 3 thresholds/step, per-wave counts packed in one u64 with
// 20-bit fields, parity-buffered -> one barrier per step).
__global__ __launch_bounds__(1024) void k_topk(const float* __restrict__ confneg,
                                               const int* __restrict__ pnp,
                                               const double* __restrict__ pd0,
                                               const double* __restrict__ pd1,
                                               int* __restrict__ snp,
                                               double* __restrict__ sums,  // [NB][3] hn,pc,lc
                                               int* __restrict__ donecnt,
                                               float* __restrict__ out) {
    __shared__ unsigned long long sq[2][16];
    __shared__ int    siw[16];
    __shared__ double sdd[16];
    __shared__ int    sk;
    int tid = threadIdx.x, b = blockIdx.x;
    int lane = tid & 63, wid = tid >> 6;

    // prologue: wave 0 reduces the 35 per-chunk partials of image b
    if (wid == 0) {
        int np_ = 0; double d0 = 0.0, d1 = 0.0;
        if (lane < NCHUNK) {
            int pb = b * NCHUNK + lane;
            np_ = pnp[pb]; d0 = pd0[pb]; d1 = pd1[pb];
        }
        for (int s = 32; s > 0; s >>= 1) {
            np_ += __shfl_xor(np_, s, 64);
            d0  += __shfl_xor(d0, s, 64);
            d1  += __shfl_xor(d1, s, 64);
        }
        if (lane == 0) {
            int k = np_ * 3; if (k > NP) k = NP;
            sk = k;
            snp[b] = np_;
            sums[b * 3 + 1] = d0;
            sums[b * 3 + 2] = d1;
        }
    }

    const float* src = confneg + (size_t)b * NP;
    float val[9];
#pragma unroll
    for (int j = 0; j < 9; ++j) {
        int i = tid + j * 1024;
        val[j] = (i < NP) ? src[i] : 0.0f;  // 0 never counts (cand>0)
    }
    __syncthreads();
    int k = sk;

    double hn = 0.0;
    if (k > 0) {   // block-uniform
        unsigned T = 0;
        int par = 0;
        // step 1: bit 30 (radix-2)
        {
            unsigned cand = 1u << 30;
            int cnt = 0;
#pragma unroll
            for (int j = 0; j < 9; ++j)
                cnt += __popcll(__ballot(__float_as_uint(val[j]) >= cand));
            if (lane == 0) sq[par][wid] = (unsigned long long)cnt;
            __syncthreads();
            unsigned long long t = 0;
#pragma unroll
            for (int w = 0; w < 16; ++w) t += sq[par][w];
            par ^= 1;
            if ((int)t >= k) T = cand;
        }
        // 15 radix-4 steps over bit pairs (29,28)...(1,0)
        for (int sh = 28; sh >= 0; sh -= 2) {
            unsigned c1 = T | (1u << sh), c2 = T | (2u << sh), c3 = T | (3u << sh);
            int n1 = 0, n2 = 0, n3 = 0;
#pragma unroll
            for (int j = 0; j < 9; ++j) {
                unsigned u = __float_as_uint(val[j]);
                n1 += __popcll(__ballot(u >= c1));
                n2 += __popcll(__ballot(u >= c2));
                n3 += __popcll(__ballot(u >= c3));
            }
            if (lane == 0)
                sq[par][wid] = (unsigned long long)n1 |
                               ((unsigned long long)n2 << 20) |
                               ((unsigned long long)n3 << 40);
            __syncthreads();
            unsigned long long t = 0;
#pragma unroll
            for (int w = 0; w < 16; ++w) t += sq[par][w];
            par ^= 1;
            int t1 = (int)(t & 0xFFFFF), t2 = (int)((t >> 20) & 0xFFFFF),
                t3 = (int)((t >> 40) & 0xFFFFF);
            if      (t3 >= k) T = c3;
            else if (t2 >= k) T = c2;
            else if (t1 >= k) T = c1;   // uniform decision
        }

        int cgt = 0;
        double sgt = 0.0;
#pragma unroll
        for (int j = 0; j < 9; ++j) {
            unsigned u = __float_as_uint(val[j]);
            if (u > T) { cgt++; sgt += (double)val[j]; }
        }
        for (int s = 32; s > 0; s >>= 1) {
            cgt += __shfl_xor(cgt, s, 64);
            sgt += __shfl_xor(sgt, s, 64);
        }
        if (lane == 0) { siw[wid] = cgt; sdd[wid] = sgt; }
        __syncthreads();
        if (tid == 0) {
            int cg = 0; double sg = 0.0;
            for (int w = 0; w < 16; ++w) { cg += siw[w]; sg += sdd[w]; }
            hn = sg + (double)(k - cg) * (double)__uint_as_float(T);
        }
    }
    if (tid == 0) sums[b * 3 + 0] = hn;  // explicit 0 when k<=0 (overwrite poison)

    // ---- last-block final reduction ----
    __shared__ int samlast;
    if (tid == 0) {
        __threadfence();                   // sums/snp stores visible device-wide
        int prev = atomicAdd(donecnt, 1);  // device-scope
        samlast = (prev == NB - 1) ? 1 : 0;
    }
    __syncthreads();
    if (!samlast) return;
    __threadfence();

    double hnn = 0.0, pc = 0.0, lc = 0.0, npd = 0.0;
    if (tid < NB) {   // peer-written: atomic reads to dodge stale caches
        hnn = atomicAdd(&sums[tid * 3 + 0], 0.0);
        pc  = atomicAdd(&sums[tid * 3 + 1], 0.0);
        lc  = atomicAdd(&sums[tid * 3 + 2], 0.0);
        npd = (double)atomicAdd((int*)&snp[tid], 0);
    }
    for (int s = 32; s > 0; s >>= 1) {
        hnn += __shfl_xor(hnn, s, 64);
        pc  += __shfl_xor(pc, s, 64);
        lc  += __shfl_xor(lc, s, 64);
        npd += __shfl_xor(npd, s, 64);
    }
    __shared__ double sfin[4][2];
    if (lane == 0 && wid < 2) {
        sfin[0][wid] = hnn; sfin[1][wid] = pc; sfin[2][wid] = lc; sfin[3][wid] = npd;
    }
    __syncthreads();
    if (tid == 0) {
        double H  = sfin[0][0] + sfin[0][1];
        double P  = sfin[1][0] + sfin[1][1];
        double L  = sfin[2][0] + sfin[2][1];
        double nt = sfin[3][0] + sfin[3][1];
        out[0] = (float)((H + P) / nt + L / (nt * 4.0));
    }
}

extern "C" void kernel_launch(void* const* d_in, const int* in_sizes, int n_in,
                              void* d_out, int out_size, void* d_ws, size_t ws_size,
                              hipStream_t stream) {
    const float* plocs  = (const float*)d_in[0];
    const float* scores = (const float*)d_in[1];
    const float* boxes  = (const float*)d_in[2];
    const int*   labels = (const int*)d_in[3];
    const float* priors = (const float*)d_in[4];
    float* out = (float*)d_out;

    char* ws = (char*)d_ws;
    int*    pfor    = (int*)ws;
    double* pd0     = (double*)(ws + 16384);
    double* pd1     = (double*)(ws + 52224);
    int*    pnp     = (int*)(ws + 88064);
    int*    snp     = (int*)(ws + 105984);
    double* sums    = (double*)(ws + 106496);
    int*    donecnt = (int*)(ws + 109568);
    float*  confneg = (float*)(ws + 109824);

    hipLaunchKernelGGL(k_obj, dim3(NO / 4, NB), dim3(256), 0, stream,
                       boxes, priors, pfor);
    hipLaunchKernelGGL(k_loss, dim3(NCHUNK, NB), dim3(256), 0, stream,
                       plocs, scores, boxes, labels, priors, pfor,
                       confneg, pnp, pd0, pd1, donecnt);
    hipLaunchKernelGGL(k_topk, dim3(NB), dim3(1024), 0, stream,
                       confneg, pnp, pd0, pd1, snp, sums, donecnt, out);
}